// Round 5
// baseline (1151.453 us; speedup 1.0000x reference)
//
#include <hip/hip_runtime.h>
#include <hip/hip_bf16.h>
#include <math.h>

// Problem constants
#define Bsz   256
#define INDIM 2048
#define Dd    128
#define Kq    65536
#define NH    32
#define S1n   16
#define S2n   16
#define ROWLEN (1 + Kq + S1n + S2n)   // 65569
#define CAP   2048                     // finalize candidate cap
#define CAPL  6144                     // topcand LDS collection cap
#define NCHUNK 8                       // split-K chunks of 256 for encoder GEMM
#define CK    256                      // K per chunk

typedef __attribute__((ext_vector_type(8))) short short8;
typedef __attribute__((ext_vector_type(4))) float f32x4;
typedef float float4a __attribute__((ext_vector_type(4), aligned(4)));
union U16x8 { uint4 u4; short8 s8; };

static __device__ inline unsigned short bf16rne(float f) {
    unsigned u = __float_as_uint(f);
    unsigned r = (u + 0x7FFFu + ((u >> 16) & 1u)) >> 16;
    return (unsigned short)r;
}
static __device__ inline unsigned fkey(float f) {   // monotone uint key
    unsigned u = __float_as_uint(f);
    return (u & 0x80000000u) ? ~u : (u | 0x80000000u);
}
static __device__ inline float funkey(unsigned key) {
    unsigned u = (key & 0x80000000u) ? (key & 0x7FFFFFFFu) : ~key;
    return __uint_as_float(u);
}

// ---------------- Kernel A1: fp64 split-K encoder GEMM ----------------
__global__ __launch_bounds__(256) void moco_a1(const float* __restrict__ q,
                                               const float* __restrict__ k,
                                               const float* __restrict__ Wq,
                                               const float* __restrict__ Wk,
                                               double* __restrict__ part) {
    int kc    = blockIdx.x;        // 0..NCHUNK-1
    int grp   = blockIdx.y;        // 0..63
    int vrow0 = grp * 8;
    bool isK  = (vrow0 >= Bsz);
    const float* inp = isK ? k : q;
    int row0 = isK ? (vrow0 - Bsz) : vrow0;
    int i0 = kc * CK;

    __shared__ float s_in[8 * CK];
    for (int idx = threadIdx.x; idx < 8 * CK; idx += 256) {
        int rr = idx >> 8, ii = idx & (CK - 1);
        s_in[idx] = inp[(size_t)(row0 + rr) * INDIM + i0 + ii];
    }
    __syncthreads();

    int dt = threadIdx.x & 31;
    int rt = threadIdx.x >> 5;
    int d0 = dt * 4;
    const float* baseWq = Wq + (size_t)i0 * Dd + d0;
    const float* baseWk = Wk + (size_t)i0 * Dd + d0;
    const float* srow = &s_in[rt * CK];

    double accA0 = 0, accA1 = 0, accA2 = 0, accA3 = 0;
    double res0, res1, res2, res3;

    if (isK) {
        double accB0 = 0, accB1 = 0, accB2 = 0, accB3 = 0;
        #pragma unroll 4
        for (int i = 0; i < CK; ++i) {
            float4 wk = *(const float4*)(baseWk + (size_t)i * Dd);
            float4 wq = *(const float4*)(baseWq + (size_t)i * Dd);
            double a = (double)srow[i];
            accA0 += a * (double)wk.x; accA1 += a * (double)wk.y;
            accA2 += a * (double)wk.z; accA3 += a * (double)wk.w;
            accB0 += a * (double)wq.x; accB1 += a * (double)wq.y;
            accB2 += a * (double)wq.z; accB3 += a * (double)wq.w;
        }
        const double M = 0.999, OM = 1.0 - 0.999;
        res0 = M * accA0 + OM * accB0;
        res1 = M * accA1 + OM * accB1;
        res2 = M * accA2 + OM * accB2;
        res3 = M * accA3 + OM * accB3;
    } else {
        #pragma unroll 8
        for (int i = 0; i < CK; ++i) {
            float4 wq = *(const float4*)(baseWq + (size_t)i * Dd);
            double a = (double)srow[i];
            accA0 += a * (double)wq.x; accA1 += a * (double)wq.y;
            accA2 += a * (double)wq.z; accA3 += a * (double)wq.w;
        }
        res0 = accA0; res1 = accA1; res2 = accA2; res3 = accA3;
    }
    double* pout = part + (((size_t)kc * 512) + vrow0 + rt) * Dd + d0;
    pout[0] = res0; pout[1] = res1; pout[2] = res2; pout[3] = res3;
}

// ---------------- Kernel A2: combine, normalize (f64), pos logit, labels, bf16 out_q ----
__global__ __launch_bounds__(128) void moco_a2(const double* __restrict__ part,
                                               double* __restrict__ outq64,
                                               unsigned short* __restrict__ outq16,
                                               unsigned* __restrict__ rowmaxkey,
                                               float* __restrict__ out) {
    int b = blockIdx.x, d = threadIdx.x;
    if (b < 2) rowmaxkey[b * 128 + d] = 0;   // init for gemmB's atomicMax
    double sq = 0, sk = 0;
    #pragma unroll
    for (int kc = 0; kc < NCHUNK; ++kc) {
        sq += part[(((size_t)kc * 512) + b) * Dd + d];
        sk += part[(((size_t)kc * 512) + Bsz + b) * Dd + d];
    }
    __shared__ double red[128];
    red[d] = sq * sq; __syncthreads();
    for (int s = 64; s > 0; s >>= 1) { if (d < s) red[d] += red[d + s]; __syncthreads(); }
    double nq = sqrt(red[0]); __syncthreads();
    red[d] = sk * sk; __syncthreads();
    for (int s = 64; s > 0; s >>= 1) { if (d < s) red[d] += red[d + s]; __syncthreads(); }
    double nk = sqrt(red[0]); __syncthreads();

    double oq = sq / fmax(nq, 1e-12);
    double ok = sk / fmax(nk, 1e-12);
    outq64[(size_t)b * Dd + d] = oq;
    outq16[(size_t)b * Dd + d] = bf16rne((float)oq);

    red[d] = oq * ok; __syncthreads();
    for (int s = 64; s > 0; s >>= 1) { if (d < s) red[d] += red[d + s]; __syncthreads(); }
    if (d == 0) {
        out[(size_t)b * ROWLEN] = (float)(red[0] / 0.07);
        ((int*)out)[(size_t)Bsz * ROWLEN + b] = 0;   // labels
    }
}

// ---------------- Kernel B: bf16 MFMA GEMM + per-row max -> out[:,1:1+K] -------
#define GB_BN 64
__global__ __launch_bounds__(256) void moco_gemmB(const unsigned short* __restrict__ outq16,
                                                  const float* __restrict__ Q,
                                                  unsigned* __restrict__ rowmaxkey,
                                                  float* __restrict__ out) {
    int bn0 = blockIdx.x * GB_BN;
    int tid = threadIdx.x;
    int w = tid >> 6, lane = tid & 63;
    int quad = lane >> 4, l16 = lane & 15;

    __shared__ unsigned short q_lds[64 * 136];   // stride 136 bf16
    __shared__ unsigned s_rmax[256];
    s_rmax[tid] = 0;

    // stage Q tile: 64 rows x 128 k, convert fp32->bf16 (RNE)
    #pragma unroll
    for (int it = 0; it < 4; ++it) {
        int chunk = tid + it * 256;          // 0..1023
        int row = chunk >> 4, kb = chunk & 15;
        const float4* g = (const float4*)(Q + (size_t)(bn0 + row) * Dd + kb * 8);
        float4 f0 = g[0], f1 = g[1];
        uint4 pk;
        pk.x = ((unsigned)bf16rne(f0.y) << 16) | bf16rne(f0.x);
        pk.y = ((unsigned)bf16rne(f0.w) << 16) | bf16rne(f0.z);
        pk.z = ((unsigned)bf16rne(f1.y) << 16) | bf16rne(f1.x);
        pk.w = ((unsigned)bf16rne(f1.w) << 16) | bf16rne(f1.z);
        *(uint4*)&q_lds[row * 136 + kb * 8] = pk;
    }

    // A fragments from global bf16 (L2-hot 64 KB)
    short8 afr[4][4];
    #pragma unroll
    for (int i = 0; i < 4; ++i)
        #pragma unroll
        for (int kc = 0; kc < 4; ++kc) {
            U16x8 u;
            u.u4 = *(const uint4*)(outq16 + (size_t)(w * 64 + i * 16 + l16) * Dd + kc * 32 + quad * 8);
            afr[i][kc] = u.s8;
        }
    __syncthreads();

    f32x4 acc[4][4];
    #pragma unroll
    for (int i = 0; i < 4; ++i)
        #pragma unroll
        for (int j = 0; j < 4; ++j)
            acc[i][j] = (f32x4){0.f, 0.f, 0.f, 0.f};

    #pragma unroll
    for (int kc = 0; kc < 4; ++kc) {
        short8 bfr[4];
        #pragma unroll
        for (int j = 0; j < 4; ++j)
            bfr[j] = *(const short8*)&q_lds[(j * 16 + l16) * 136 + kc * 32 + quad * 8];
        #pragma unroll
        for (int i = 0; i < 4; ++i)
            #pragma unroll
            for (int j = 0; j < 4; ++j)
                acc[i][j] = __builtin_amdgcn_mfma_f32_16x16x32_bf16(afr[i][kc], bfr[j], acc[i][j], 0, 0, 0);
    }

    const float invT = (float)(1.0 / 0.07);
    #pragma unroll
    for (int i = 0; i < 4; ++i) {
        int rbase = w * 64 + i * 16 + quad * 4;
        #pragma unroll
        for (int reg = 0; reg < 4; ++reg) {
            size_t ro = (size_t)(rbase + reg) * ROWLEN + 1 + bn0;
            float v0 = acc[i][0][reg] * invT;
            float v1 = acc[i][1][reg] * invT;
            float v2 = acc[i][2][reg] * invT;
            float v3 = acc[i][3][reg] * invT;
            out[ro + l16]      = v0;
            out[ro + 16 + l16] = v1;
            out[ro + 32 + l16] = v2;
            out[ro + 48 + l16] = v3;
            float m = fmaxf(fmaxf(v0, v1), fmaxf(v2, v3));
            atomicMax(&s_rmax[rbase + reg], fkey(m));
        }
    }
    __syncthreads();
    // conditional global max: monotone, so a stale read only adds one atomic
    unsigned cur = rowmaxkey[tid];
    unsigned mine = s_rmax[tid];
    if (mine > cur) atomicMax(&rowmaxkey[tid], mine);
}

// ---------------- Kernel C: single-pass candidate collection via rowmax window ----
__global__ __launch_bounds__(512) void moco_topcand(const float* __restrict__ out,
                                                    const unsigned* __restrict__ rowmaxkey,
                                                    int* __restrict__ cand,
                                                    int* __restrict__ ccnt) {
    int row = blockIdx.x;
    int t = threadIdx.x;
    const float* p = out + (size_t)row * ROWLEN + 1;
    __shared__ float lv[CAPL];
    __shared__ int   li[CAPL];
    __shared__ unsigned hist[512];
    __shared__ int s_cnt, s_thr;

    float vmax = funkey(rowmaxkey[row]);
    float W = 2.0f;
    int cnt = 0;
    const float4a* p4 = (const float4a*)p;

    for (int attempt = 0; attempt < 5; ++attempt) {
        if (t == 0) s_cnt = 0;
        __syncthreads();
        float thresh = vmax - W;
        #pragma unroll 8
        for (int it = 0; it < 32; ++it) {
            int vi = t + it * 512;              // < 16384
            float4a v = p4[vi];
            #pragma unroll
            for (int e = 0; e < 4; ++e) {
                float f = v[e];
                if (f >= thresh) {
                    int pos = atomicAdd(&s_cnt, 1);
                    if (pos < CAPL) { lv[pos] = f; li[pos] = vi * 4 + e; }
                }
            }
        }
        __syncthreads();
        cnt = s_cnt;
        if (cnt >= NH && cnt <= CAPL) break;
        W = (cnt > CAPL) ? W * 0.5f : W * 2.0f;
        __syncthreads();
    }
    if (cnt > CAPL) cnt = CAPL;   // pathological safety

    int wcnt;
    if (cnt > CAP) {
        // prune via 512-bin histogram over [vmax-W, vmax], keep >= rank-NH bin - margin
        hist[t & 511] = 0;
        __syncthreads();
        float lo = vmax - W;
        float scale = 512.0f / W;
        for (int c = t; c < cnt; c += 512) {
            int b = (int)((lv[c] - lo) * scale);
            b = b < 0 ? 0 : (b > 511 ? 511 : b);
            atomicAdd(&hist[b], 1u);
        }
        __syncthreads();
        if (t == 0) {
            unsigned cum = 0; int b = 511;
            for (; b > 0; --b) { cum += hist[b]; if (cum >= NH) break; }
            int mb = (int)(0.2f * scale) + 1;    // bf16-ordering safety margin
            b -= mb; if (b < 0) b = 0;
            long total = 0;
            for (int x = 511; x >= b; --x) total += hist[x];
            while (total > CAP && b < 511) { total -= hist[b]; ++b; }
            s_thr = b;
            s_cnt = 0;
        }
        __syncthreads();
        float thresh2 = (vmax - W) + (float)s_thr * (W / 512.0f);
        for (int c = t; c < cnt; c += 512) {
            if (lv[c] >= thresh2) {
                int pos = atomicAdd(&s_cnt, 1);
                if (pos < CAP) cand[(size_t)row * CAP + pos] = li[c];
            }
        }
        __syncthreads();
        wcnt = s_cnt < CAP ? s_cnt : CAP;
    } else {
        for (int c = t; c < cnt; c += 512) cand[(size_t)row * CAP + c] = li[c];
        wcnt = cnt;
    }
    if (t == 0) ccnt[row] = wcnt;
}

// ---------------- Kernel D: wave-cooperative fp64 re-rank + mixed-negative logits ----
// Every queue-row access is coalesced: one float2 per lane = whole 512B row per
// wave-instruction; f64 shuffle-tree reduction.
__global__ __launch_bounds__(256) void moco_finalize(const double* __restrict__ outq64,
                                                     const float* __restrict__ Qm,
                                                     const int* __restrict__ cand,
                                                     const int* __restrict__ ccnt,
                                                     const float* __restrict__ alpha,
                                                     const float* __restrict__ beta,
                                                     const int* __restrict__ i1a,
                                                     const int* __restrict__ i1b,
                                                     const int* __restrict__ i2,
                                                     float* __restrict__ out) {
    int row = blockIdx.x;
    int t = threadIdx.x;
    int w = t >> 6, lane = t & 63;
    __shared__ double oq[Dd];
    __shared__ double dval[CAP];
    __shared__ int didx[CAP];
    __shared__ int hard[NH];

    if (t < Dd) oq[t] = outq64[(size_t)row * Dd + t];
    __syncthreads();

    int n = ccnt[row]; if (n > CAP) n = CAP;
    double o0 = oq[2 * lane], o1 = oq[2 * lane + 1];

    // wave-cooperative candidate dots
    for (int c = w; c < n; c += 4) {
        int idx = cand[(size_t)row * CAP + c];
        float2 v = ((const float2*)(Qm + (size_t)idx * Dd))[lane];
        double p = o0 * (double)v.x + o1 * (double)v.y;
        #pragma unroll
        for (int off = 32; off > 0; off >>= 1) p += __shfl_down(p, off, 64);
        if (lane == 0) { dval[c] = p / 0.07; didx[c] = idx; }
    }
    __syncthreads();

    // exact rank (ties -> lower index first, matching lax.top_k)
    for (int c = t; c < n; c += 256) {
        double v = dval[c]; int id = didx[c];
        int r = 0;
        for (int j = 0; j < n; ++j) {
            double vj = dval[j];
            r += (vj > v) || (vj == v && didx[j] < id);
        }
        if (r < NH) hard[r] = id;
    }
    __syncthreads();

    // wave-cooperative mixed negatives: mix m in [0,32), wave handles m = w+4*it
    for (int m = w; m < S1n + S2n; m += 4) {
        double nn, qd;
        if (m < S1n) {
            double a = (double)alpha[(size_t)row * S1n + m];
            int g1 = hard[i1a[(size_t)row * S1n + m]];
            int g2 = hard[i1b[(size_t)row * S1n + m]];
            float2 x1 = ((const float2*)(Qm + (size_t)g1 * Dd))[lane];
            float2 x2 = ((const float2*)(Qm + (size_t)g2 * Dd))[lane];
            double m0 = a * (double)x1.x + (1.0 - a) * (double)x2.x;
            double m1 = a * (double)x1.y + (1.0 - a) * (double)x2.y;
            nn = m0 * m0 + m1 * m1;
            qd = o0 * m0 + o1 * m1;
        } else {
            int s = m - S1n;
            double bb = (double)beta[(size_t)row * S2n + s] * 0.5;
            int g = hard[i2[(size_t)row * S2n + s]];
            float2 xg = ((const float2*)(Qm + (size_t)g * Dd))[lane];
            double m0 = bb * o0 + (1.0 - bb) * (double)xg.x;
            double m1 = bb * o1 + (1.0 - bb) * (double)xg.y;
            nn = m0 * m0 + m1 * m1;
            qd = o0 * m0 + o1 * m1;
        }
        #pragma unroll
        for (int off = 32; off > 0; off >>= 1) {
            nn += __shfl_down(nn, off, 64);
            qd += __shfl_down(qd, off, 64);
        }
        if (lane == 0)
            out[(size_t)row * ROWLEN + 1 + Kq + m] =
                (float)(qd / fmax(sqrt(nn), 1e-12) / 0.07);
    }
}

extern "C" void kernel_launch(void* const* d_in, const int* in_sizes, int n_in,
                              void* d_out, int out_size, void* d_ws, size_t ws_size,
                              hipStream_t stream) {
    const float* q     = (const float*)d_in[0];
    const float* k     = (const float*)d_in[1];
    const float* Wq    = (const float*)d_in[2];
    const float* Wk    = (const float*)d_in[3];
    const float* queue = (const float*)d_in[4];
    const float* alpha = (const float*)d_in[5];
    const float* beta  = (const float*)d_in[6];
    const int*   i1a   = (const int*)d_in[7];
    const int*   i1b   = (const int*)d_in[8];
    const int*   i2    = (const int*)d_in[9];
    float* out = (float*)d_out;

    // workspace: part (4 MB, dead after a2) aliases cand (2 MB, born in topcand)
    char* ws = (char*)d_ws;
    double* part   = (double*)(ws);                        // 8*512*128*8 = 4,194,304
    int*    cand   = (int*)(ws);                           // 256*2048*4  = 2,097,152 (alias)
    double* outq64 = (double*)(ws + 4194304);              // 262,144
    unsigned short* outq16 = (unsigned short*)(ws + 4194304 + 262144); // 65,536
    int*    ccnt   = (int*)(ws + 4194304 + 262144 + 65536);            // 1,024
    unsigned* rowmaxkey = (unsigned*)(ws + 4194304 + 262144 + 65536 + 1024); // 1,024

    moco_a1<<<dim3(NCHUNK, 64), 256, 0, stream>>>(q, k, Wq, Wk, part);
    moco_a2<<<dim3(Bsz), 128, 0, stream>>>(part, outq64, outq16, rowmaxkey, out);
    moco_gemmB<<<dim3(Kq / GB_BN), 256, 0, stream>>>(outq16, queue, rowmaxkey, out);
    moco_topcand<<<dim3(Bsz), 512, 0, stream>>>(out, rowmaxkey, cand, ccnt);
    moco_finalize<<<dim3(Bsz), 256, 0, stream>>>(outq64, queue, cand, ccnt,
                                                 alpha, beta, i1a, i1b, i2, out);
}

// Round 6
// 263.281 us; speedup vs baseline: 4.3735x; 4.3735x over previous
//
#include <hip/hip_runtime.h>
#include <hip/hip_bf16.h>
#include <math.h>

// Problem constants
#define Bsz   256
#define INDIM 2048
#define Dd    128
#define Kq    65536
#define NH    32
#define S1n   16
#define S2n   16
#define ROWLEN (1 + Kq + S1n + S2n)   // 65569
#define CAP   2048                     // finalize candidate cap
#define CAPL  6144                     // topcand LDS collection cap
#define NCHUNK 8                       // split-K chunks of 256 for encoder GEMM
#define CK    256                      // K per chunk

typedef __attribute__((ext_vector_type(8))) short short8;
typedef __attribute__((ext_vector_type(4))) float f32x4;
typedef float float4a __attribute__((ext_vector_type(4), aligned(4)));
union U16x8 { uint4 u4; short8 s8; };

static __device__ inline unsigned short bf16rne(float f) {
    unsigned u = __float_as_uint(f);
    unsigned r = (u + 0x7FFFu + ((u >> 16) & 1u)) >> 16;
    return (unsigned short)r;
}
static __device__ inline unsigned fkey(float f) {   // monotone uint key
    unsigned u = __float_as_uint(f);
    return (u & 0x80000000u) ? ~u : (u | 0x80000000u);
}
static __device__ inline float funkey(unsigned key) {
    unsigned u = (key & 0x80000000u) ? (key & 0x7FFFFFFFu) : ~key;
    return __uint_as_float(u);
}

// ---------------- Kernel A1: fp64 split-K encoder GEMM ----------------
__global__ __launch_bounds__(256) void moco_a1(const float* __restrict__ q,
                                               const float* __restrict__ k,
                                               const float* __restrict__ Wq,
                                               const float* __restrict__ Wk,
                                               double* __restrict__ part) {
    int kc    = blockIdx.x;        // 0..NCHUNK-1
    int grp   = blockIdx.y;        // 0..63
    int vrow0 = grp * 8;
    bool isK  = (vrow0 >= Bsz);
    const float* inp = isK ? k : q;
    int row0 = isK ? (vrow0 - Bsz) : vrow0;
    int i0 = kc * CK;

    __shared__ float s_in[8 * CK];
    for (int idx = threadIdx.x; idx < 8 * CK; idx += 256) {
        int rr = idx >> 8, ii = idx & (CK - 1);
        s_in[idx] = inp[(size_t)(row0 + rr) * INDIM + i0 + ii];
    }
    __syncthreads();

    int dt = threadIdx.x & 31;
    int rt = threadIdx.x >> 5;
    int d0 = dt * 4;
    const float* baseWq = Wq + (size_t)i0 * Dd + d0;
    const float* baseWk = Wk + (size_t)i0 * Dd + d0;
    const float* srow = &s_in[rt * CK];

    double accA0 = 0, accA1 = 0, accA2 = 0, accA3 = 0;
    double res0, res1, res2, res3;

    if (isK) {
        double accB0 = 0, accB1 = 0, accB2 = 0, accB3 = 0;
        #pragma unroll 4
        for (int i = 0; i < CK; ++i) {
            float4 wk = *(const float4*)(baseWk + (size_t)i * Dd);
            float4 wq = *(const float4*)(baseWq + (size_t)i * Dd);
            double a = (double)srow[i];
            accA0 += a * (double)wk.x; accA1 += a * (double)wk.y;
            accA2 += a * (double)wk.z; accA3 += a * (double)wk.w;
            accB0 += a * (double)wq.x; accB1 += a * (double)wq.y;
            accB2 += a * (double)wq.z; accB3 += a * (double)wq.w;
        }
        const double M = 0.999, OM = 1.0 - 0.999;
        res0 = M * accA0 + OM * accB0;
        res1 = M * accA1 + OM * accB1;
        res2 = M * accA2 + OM * accB2;
        res3 = M * accA3 + OM * accB3;
    } else {
        #pragma unroll 8
        for (int i = 0; i < CK; ++i) {
            float4 wq = *(const float4*)(baseWq + (size_t)i * Dd);
            double a = (double)srow[i];
            accA0 += a * (double)wq.x; accA1 += a * (double)wq.y;
            accA2 += a * (double)wq.z; accA3 += a * (double)wq.w;
        }
        res0 = accA0; res1 = accA1; res2 = accA2; res3 = accA3;
    }
    double* pout = part + (((size_t)kc * 512) + vrow0 + rt) * Dd + d0;
    pout[0] = res0; pout[1] = res1; pout[2] = res2; pout[3] = res3;
}

// ---------------- Kernel A2: combine, normalize (f64), pos logit, labels, bf16 out_q ----
__global__ __launch_bounds__(128) void moco_a2(const double* __restrict__ part,
                                               double* __restrict__ outq64,
                                               unsigned short* __restrict__ outq16,
                                               unsigned* __restrict__ rowmaxkey,
                                               float* __restrict__ out) {
    int b = blockIdx.x, d = threadIdx.x;
    if (b < 2) rowmaxkey[b * 128 + d] = 0;   // init for gemmB's atomicMax
    double sq = 0, sk = 0;
    #pragma unroll
    for (int kc = 0; kc < NCHUNK; ++kc) {
        sq += part[(((size_t)kc * 512) + b) * Dd + d];
        sk += part[(((size_t)kc * 512) + Bsz + b) * Dd + d];
    }
    __shared__ double red[128];
    red[d] = sq * sq; __syncthreads();
    for (int s = 64; s > 0; s >>= 1) { if (d < s) red[d] += red[d + s]; __syncthreads(); }
    double nq = sqrt(red[0]); __syncthreads();
    red[d] = sk * sk; __syncthreads();
    for (int s = 64; s > 0; s >>= 1) { if (d < s) red[d] += red[d + s]; __syncthreads(); }
    double nk = sqrt(red[0]); __syncthreads();

    double oq = sq / fmax(nq, 1e-12);
    double ok = sk / fmax(nk, 1e-12);
    outq64[(size_t)b * Dd + d] = oq;
    outq16[(size_t)b * Dd + d] = bf16rne((float)oq);

    red[d] = oq * ok; __syncthreads();
    for (int s = 64; s > 0; s >>= 1) { if (d < s) red[d] += red[d + s]; __syncthreads(); }
    if (d == 0) {
        out[(size_t)b * ROWLEN] = (float)(red[0] / 0.07);
        ((int*)out)[(size_t)Bsz * ROWLEN + b] = 0;   // labels
    }
}

// ---------------- Kernel B: bf16 MFMA GEMM + per-row max -> out[:,1:1+K] -------
#define GB_BN 64
__global__ __launch_bounds__(256) void moco_gemmB(const unsigned short* __restrict__ outq16,
                                                  const float* __restrict__ Q,
                                                  unsigned* __restrict__ rowmaxkey,
                                                  float* __restrict__ out) {
    int bn0 = blockIdx.x * GB_BN;
    int tid = threadIdx.x;
    int w = tid >> 6, lane = tid & 63;
    int quad = lane >> 4, l16 = lane & 15;

    __shared__ unsigned short q_lds[64 * 136];   // stride 136 bf16
    __shared__ unsigned s_rmax[256];
    s_rmax[tid] = 0;

    // stage Q tile: 64 rows x 128 k, convert fp32->bf16 (RNE)
    #pragma unroll
    for (int it = 0; it < 4; ++it) {
        int chunk = tid + it * 256;          // 0..1023
        int row = chunk >> 4, kb = chunk & 15;
        const float4* g = (const float4*)(Q + (size_t)(bn0 + row) * Dd + kb * 8);
        float4 f0 = g[0], f1 = g[1];
        uint4 pk;
        pk.x = ((unsigned)bf16rne(f0.y) << 16) | bf16rne(f0.x);
        pk.y = ((unsigned)bf16rne(f0.w) << 16) | bf16rne(f0.z);
        pk.z = ((unsigned)bf16rne(f1.y) << 16) | bf16rne(f1.x);
        pk.w = ((unsigned)bf16rne(f1.w) << 16) | bf16rne(f1.z);
        *(uint4*)&q_lds[row * 136 + kb * 8] = pk;
    }

    // A fragments from global bf16 (L2-hot 64 KB)
    short8 afr[4][4];
    #pragma unroll
    for (int i = 0; i < 4; ++i)
        #pragma unroll
        for (int kc = 0; kc < 4; ++kc) {
            U16x8 u;
            u.u4 = *(const uint4*)(outq16 + (size_t)(w * 64 + i * 16 + l16) * Dd + kc * 32 + quad * 8);
            afr[i][kc] = u.s8;
        }
    __syncthreads();

    f32x4 acc[4][4];
    #pragma unroll
    for (int i = 0; i < 4; ++i)
        #pragma unroll
        for (int j = 0; j < 4; ++j)
            acc[i][j] = (f32x4){0.f, 0.f, 0.f, 0.f};

    #pragma unroll
    for (int kc = 0; kc < 4; ++kc) {
        short8 bfr[4];
        #pragma unroll
        for (int j = 0; j < 4; ++j)
            bfr[j] = *(const short8*)&q_lds[(j * 16 + l16) * 136 + kc * 32 + quad * 8];
        #pragma unroll
        for (int i = 0; i < 4; ++i)
            #pragma unroll
            for (int j = 0; j < 4; ++j)
                acc[i][j] = __builtin_amdgcn_mfma_f32_16x16x32_bf16(afr[i][kc], bfr[j], acc[i][j], 0, 0, 0);
    }

    const float invT = (float)(1.0 / 0.07);
    #pragma unroll
    for (int i = 0; i < 4; ++i) {
        int rbase = w * 64 + i * 16 + quad * 4;
        #pragma unroll
        for (int reg = 0; reg < 4; ++reg) {
            size_t ro = (size_t)(rbase + reg) * ROWLEN + 1 + bn0;
            float v0 = acc[i][0][reg] * invT;
            float v1 = acc[i][1][reg] * invT;
            float v2 = acc[i][2][reg] * invT;
            float v3 = acc[i][3][reg] * invT;
            out[ro + l16]      = v0;
            out[ro + 16 + l16] = v1;
            out[ro + 32 + l16] = v2;
            out[ro + 48 + l16] = v3;
            float m = fmaxf(fmaxf(v0, v1), fmaxf(v2, v3));
            atomicMax(&s_rmax[rbase + reg], fkey(m));
        }
    }
    __syncthreads();
    // conditional global max: monotone, so a stale read only adds one atomic
    unsigned cur = rowmaxkey[tid];
    unsigned mine = s_rmax[tid];
    if (mine > cur) atomicMax(&rowmaxkey[tid], mine);
}

// ---------------- Kernel C: single-pass window collection + fine LDS prune ----
// Stage 1: collect all values >= vmax - W into LDS (cnt ~ 300).
// Stage 2: 128-bin fine histogram over [vmax-W, vmax]; keep values above the
// rank-NH bin minus a 0.25-logit-unit margin (covers bf16-vs-f64 reorder,
// measured error 0.031; margin validated by R3/R4/R5 passes). Delivers
// n ~ 33-60 to finalize.
__global__ __launch_bounds__(512) void moco_topcand(const float* __restrict__ out,
                                                    const unsigned* __restrict__ rowmaxkey,
                                                    int* __restrict__ cand,
                                                    int* __restrict__ ccnt) {
    int row = blockIdx.x;
    int t = threadIdx.x;
    const float* p = out + (size_t)row * ROWLEN + 1;
    __shared__ float lv[CAPL];
    __shared__ int   li[CAPL];
    __shared__ unsigned hist[128];
    __shared__ int s_cnt, s_thr;

    float vmax = funkey(rowmaxkey[row]);
    float W = 2.0f;
    int cnt = 0;
    const float4a* p4 = (const float4a*)p;

    for (int attempt = 0; attempt < 5; ++attempt) {
        if (t == 0) s_cnt = 0;
        __syncthreads();
        float thresh = vmax - W;
        #pragma unroll 8
        for (int it = 0; it < 32; ++it) {
            int vi = t + it * 512;              // < 16384
            float4a v = p4[vi];
            #pragma unroll
            for (int e = 0; e < 4; ++e) {
                float f = v[e];
                if (f >= thresh) {
                    int pos = atomicAdd(&s_cnt, 1);
                    if (pos < CAPL) { lv[pos] = f; li[pos] = vi * 4 + e; }
                }
            }
        }
        __syncthreads();
        cnt = s_cnt;
        if (cnt >= NH && cnt <= CAPL) break;
        W = (cnt > CAPL) ? W * 0.5f : W * 2.0f;
        __syncthreads();
    }
    if (cnt > CAPL) cnt = CAPL;   // pathological safety

    // ---- stage 2: fine prune (always) ----
    if (t < 128) hist[t] = 0;
    __syncthreads();
    float lo = vmax - W;
    float scale = 128.0f / W;
    for (int c = t; c < cnt; c += 512) {
        int b = (int)((lv[c] - lo) * scale);
        b = b < 0 ? 0 : (b > 127 ? 127 : b);
        atomicAdd(&hist[b], 1u);
    }
    __syncthreads();
    if (t == 0) {
        unsigned cum = 0; int b = 127;
        for (; b > 0; --b) { cum += hist[b]; if (cum >= NH) break; }
        int mb = (int)(0.25f * scale) + 1;     // 0.25 logit-unit safety margin
        b -= mb; if (b < 0) b = 0;
        long total = 0;
        for (int x = 127; x >= b; --x) total += hist[x];
        while (total > CAP && b < 127) { total -= hist[b]; ++b; }
        s_thr = b;
        s_cnt = 0;
    }
    __syncthreads();
    float thresh2 = lo + (float)s_thr * (W / 128.0f);
    for (int c = t; c < cnt; c += 512) {
        if (lv[c] >= thresh2) {
            int pos = atomicAdd(&s_cnt, 1);
            if (pos < CAP) cand[(size_t)row * CAP + pos] = li[c];
        }
    }
    __syncthreads();
    if (t == 0) ccnt[row] = (s_cnt < CAP) ? s_cnt : CAP;
}

// ---------------- Kernel D: fp64 re-rank + mixed-negative logits (R3-verbatim) ----
__global__ __launch_bounds__(256) void moco_finalize(const double* __restrict__ outq64,
                                                     const float* __restrict__ Qm,
                                                     const int* __restrict__ cand,
                                                     const int* __restrict__ ccnt,
                                                     const float* __restrict__ alpha,
                                                     const float* __restrict__ beta,
                                                     const int* __restrict__ i1a,
                                                     const int* __restrict__ i1b,
                                                     const int* __restrict__ i2,
                                                     float* __restrict__ out) {
    int row = blockIdx.x;
    __shared__ double oq[Dd];
    __shared__ double dval[CAP];
    __shared__ int didx[CAP];
    __shared__ int hard[NH];

    for (int i = threadIdx.x; i < Dd; i += 256) oq[i] = outq64[(size_t)row * Dd + i];
    __syncthreads();

    int n = ccnt[row]; if (n > CAP) n = CAP;
    for (int c = threadIdx.x; c < n; c += 256) {
        int idx = cand[(size_t)row * CAP + c];
        const float* qr = Qm + (size_t)idx * Dd;
        double dot = 0;
        #pragma unroll 4
        for (int i = 0; i < Dd; ++i) dot += oq[i] * (double)qr[i];
        dval[c] = dot / 0.07;
        didx[c] = idx;
    }
    __syncthreads();

    // exact rank (ties -> lower index first, matching lax.top_k)
    for (int c = threadIdx.x; c < n; c += 256) {
        double v = dval[c]; int id = didx[c];
        int r = 0;
        for (int j = 0; j < n; ++j) {
            double vj = dval[j];
            r += (vj > v) || (vj == v && didx[j] < id);
        }
        if (r < NH) hard[r] = id;
    }
    __syncthreads();

    int t = threadIdx.x;
    if (t < S1n) {
        double a = (double)alpha[(size_t)row * S1n + t];
        int g1 = hard[i1a[(size_t)row * S1n + t]];
        int g2 = hard[i1b[(size_t)row * S1n + t]];
        const float* q1 = Qm + (size_t)g1 * Dd;
        const float* q2 = Qm + (size_t)g2 * Dd;
        double nn = 0, qd = 0;
        #pragma unroll 4
        for (int i = 0; i < Dd; ++i) {
            double m = a * (double)q1[i] + (1.0 - a) * (double)q2[i];
            nn += m * m; qd += oq[i] * m;
        }
        double logit = qd / fmax(sqrt(nn), 1e-12) / 0.07;
        out[(size_t)row * ROWLEN + 1 + Kq + t] = (float)logit;
    } else if (t < S1n + S2n) {
        int s = t - S1n;
        double bb = (double)beta[(size_t)row * S2n + s] * 0.5;
        int g = hard[i2[(size_t)row * S2n + s]];
        const float* qg = Qm + (size_t)g * Dd;
        double nn = 0, qd = 0;
        #pragma unroll 4
        for (int i = 0; i < Dd; ++i) {
            double m = bb * oq[i] + (1.0 - bb) * (double)qg[i];
            nn += m * m; qd += oq[i] * m;
        }
        double logit = qd / fmax(sqrt(nn), 1e-12) / 0.07;
        out[(size_t)row * ROWLEN + 1 + Kq + S1n + s] = (float)logit;
    }
}

extern "C" void kernel_launch(void* const* d_in, const int* in_sizes, int n_in,
                              void* d_out, int out_size, void* d_ws, size_t ws_size,
                              hipStream_t stream) {
    const float* q     = (const float*)d_in[0];
    const float* k     = (const float*)d_in[1];
    const float* Wq    = (const float*)d_in[2];
    const float* Wk    = (const float*)d_in[3];
    const float* queue = (const float*)d_in[4];
    const float* alpha = (const float*)d_in[5];
    const float* beta  = (const float*)d_in[6];
    const int*   i1a   = (const int*)d_in[7];
    const int*   i1b   = (const int*)d_in[8];
    const int*   i2    = (const int*)d_in[9];
    float* out = (float*)d_out;

    // workspace: part (4 MB, dead after a2) aliases cand (2 MB, born in topcand)
    char* ws = (char*)d_ws;
    double* part   = (double*)(ws);                        // 8*512*128*8 = 4,194,304
    int*    cand   = (int*)(ws);                           // 256*2048*4  = 2,097,152 (alias)
    double* outq64 = (double*)(ws + 4194304);              // 262,144
    unsigned short* outq16 = (unsigned short*)(ws + 4194304 + 262144); // 65,536
    int*    ccnt   = (int*)(ws + 4194304 + 262144 + 65536);            // 1,024
    unsigned* rowmaxkey = (unsigned*)(ws + 4194304 + 262144 + 65536 + 1024); // 1,024

    moco_a1<<<dim3(NCHUNK, 64), 256, 0, stream>>>(q, k, Wq, Wk, part);
    moco_a2<<<dim3(Bsz), 128, 0, stream>>>(part, outq64, outq16, rowmaxkey, out);
    moco_gemmB<<<dim3(Kq / GB_BN), 256, 0, stream>>>(outq16, queue, rowmaxkey, out);
    moco_topcand<<<dim3(Bsz), 512, 0, stream>>>(out, rowmaxkey, cand, ccnt);
    moco_finalize<<<dim3(Bsz), 256, 0, stream>>>(outq64, queue, cand, ccnt,
                                                 alpha, beta, i1a, i1b, i2, out);
}